// Round 9
// baseline (37.262 us; speedup 1.0000x reference)
//
#include <hip/hip_runtime.h>
#include <math.h>

#define T_SEQ 2048
#define DMODEL 256
#define C_HEAD 64
#define NH 4
#define NWIN 16
#define B_SZ 4

typedef __attribute__((ext_vector_type(8))) short bf16x8;
typedef __attribute__((ext_vector_type(8))) unsigned short ushort8;
typedef __attribute__((ext_vector_type(4))) float f32x4;

static __device__ __forceinline__ unsigned short f2bf(float f) {
    union { float f; unsigned int u; } v; v.f = f;
    unsigned int r = v.u + 0x7FFFu + ((v.u >> 16) & 1u);
    return (unsigned short)(r >> 16);
}

// ---------------- conv_w: pack weights fragment-major + rope table ------
// Region 1 (K=256): cols [WQ(256) WK(64) WV(64)]; Region 2 (K=128):
// cols [Wg0(64) Wg1(64) Wout(256)] at +98304. Fragment-major: every MFMA
// B-load is base + lane*16B. blocks 72..135: rope table (cos,sin).
__global__ __launch_bounds__(256) void conv_w_kernel(
    const float* __restrict__ WQ, const float* __restrict__ WK,
    const float* __restrict__ WV, const float* __restrict__ Wg0,
    const float* __restrict__ Wg1, const float* __restrict__ Wout,
    unsigned short* __restrict__ dst, float2* __restrict__ rtab) {
    const int tid = threadIdx.x;
    if (blockIdx.x >= 72) {
        const int idx = (blockIdx.x - 72) * 256 + tid;   // 0..16383
        const int t = idx >> 3, k = idx & 7;
        const float theta = powf(10000.0f, -0.125f * (float)k);
        const float fr = (float)t * theta;
        rtab[idx] = make_float2(cosf(fr), sinf(fr));
        return;
    }
    const int i = blockIdx.x * 256 + tid;               // 18432 vec8
    const float* s; long off; long doff;
    if (i < 12288) {                                    // K=256 region
        const long e = (long)i * 8;
        const int col = (int)(e >> 8), k = (int)(e & 255);
        if      (col < 256) { s = WQ; off = (long)col * 256 + k; }
        else if (col < 320) { s = WK; off = (long)(col - 256) * 256 + k; }
        else                { s = WV; off = (long)(col - 320) * 256 + k; }
        doff = ((long)(col >> 4) * 8 + (k >> 5)) * 512 + ((k >> 3) & 3) * 128 + (col & 15) * 8;
    } else {                                            // K=128 region
        const long e = (long)(i - 12288) * 8;
        const int col = (int)(e >> 7), k = (int)(e & 127);
        if      (col < 64)  { s = Wg0; off = (long)col * 128 + k; }
        else if (col < 128) { s = Wg1; off = (long)(col - 64) * 128 + k; }
        else                { s = Wout; off = (long)(col - 128) * 128 + k; }
        doff = 98304 + ((long)(col >> 4) * 4 + (k >> 5)) * 512 + ((k >> 3) & 3) * 128 + (col & 15) * 8;
    }
    const float4* s4 = (const float4*)(s + off);
    float4 a = s4[0], b = s4[1];
    ushort8 o;
    o[0] = f2bf(a.x); o[1] = f2bf(a.y); o[2] = f2bf(a.z); o[3] = f2bf(a.w);
    o[4] = f2bf(b.x); o[5] = f2bf(b.y); o[6] = f2bf(b.z); o[7] = f2bf(b.w);
    *(ushort8*)(dst + doff) = o;
}

// ---------------- fused kernel, BM=32 ----------------------------------
// grid = B*(T/32) = 256 blocks, 256 thr (4 waves). Wave h:
//   QKV: Q head h (32 tokens, acc[2][4]) + {K,V} slab (sel=h>>1) rows
//   (h&1)*32..+31 in ONE interleaved ks loop. Epilogues -> LDS.
//   Attention: 2 passes (th=0,1) of 16 tokens: S^T, softmax, P relayout,
//   PV, inverse rope -> o_lds. Gates acc[2][2]; out acc[2][4].
// LDS (60KB): staging buffer unioned with o/p tiles -> 2 blocks/CU.
__global__ __launch_bounds__(256) void fused_kernel(
    const float* __restrict__ H, const unsigned short* __restrict__ Wallb,
    const float* __restrict__ wq, const float* __restrict__ wk,
    const float* __restrict__ wv, const float2* __restrict__ rtab,
    const float* __restrict__ bg0, const float* __restrict__ bg1,
    const float* __restrict__ bout, float* __restrict__ out)
{
    __shared__ __align__(16) char smem[61440];
    char* lds_a = smem;            // bf16 [48][256] swizzled (24576 B)  [phase A]
    char* o_lds = smem;            // bf16 [32][256] swizzled (16384 B)  [reuse]
    char* p_lds = smem + 16384;    // bf16 [32][128] swizzled (8192 B)   [reuse]
    char* q_lds = smem + 24576;    // bf16 [4][32][64] swizzled (16384 B)
    char* k_lds = smem + 40960;    // bf16 [64][64] swizzled (8192 B; rows>=48 pad)
    char* v_lds = smem + 49152;    // [4 ctiles][64 keys][16 ch] swizzled (8192 B)
    char* p_att = smem + 57344;    // per-wave P buffer (4096 B)

    const int tid = threadIdx.x;
    const int blk = blockIdx.x;
    const int b  = blk >> 6;
    const int t0 = (blk & 63) << 5;

    const unsigned short* Wpk2 = Wallb + 98304;   // K=128 packed region

    // ---- stage H rows [t0-16, t0+32) (48 rows, clamped), f32->bf16 ------
    for (int idx = tid; idx < 1536; idx += 256) {
        int row = idx >> 5, ch = idx & 31;
        int t = t0 - 16 + row; if (t < 0) t = 0;       // masked later
        const float4* s4 = (const float4*)(H + ((size_t)b * T_SEQ + t) * DMODEL + ch * 8);
        float4 a = s4[0], c = s4[1];
        ushort8 o;
        o[0] = f2bf(a.x); o[1] = f2bf(a.y); o[2] = f2bf(a.z); o[3] = f2bf(a.w);
        o[4] = f2bf(c.x); o[5] = f2bf(c.y); o[6] = f2bf(c.z); o[7] = f2bf(c.w);
        int byte = row * 512 + ch * 16;
        byte ^= (row & 7) << 4;
        *(ushort8*)(lds_a + byte) = o;
    }
    __syncthreads();

    const int h  = tid >> 6;
    const int l  = tid & 63;
    const int g  = l >> 4;
    const int li = l & 15;
    const int lane16 = l * 8;      // packed-W per-lane elem offset (16B/lane)

    const int sel  = h >> 1;       // 0 = K, 1 = V
    const int base = (h & 1) * 32; // K/V slab base row (rows >=48 are garbage)

    // ---- QKV: Q head h + K/V slab, interleaved ks loop ------------------
    f32x4 accq[2][4] = {};
    f32x4 acckv[2][4] = {};
    #pragma unroll
    for (int ks = 0; ks < 8; ++ks) {
        bf16x8 aq[2], akv[2];
        #pragma unroll
        for (int mf = 0; mf < 2; ++mf) {
            const int rowq = 16 + mf * 16 + li;        // tokens
            int bq = rowq * 512 + (ks * 32 + g * 8) * 2;
            bq ^= (rowq & 7) << 4;
            aq[mf] = *(const bf16x8*)(lds_a + bq);
            const int rowk = base + mf * 16 + li;      // K/V halo rows
            int bk = rowk * 512 + (ks * 32 + g * 8) * 2;
            bk ^= (rowk & 7) << 4;
            akv[mf] = *(const bf16x8*)(lds_a + bk);    // rows>=48: garbage (safe)
        }
        #pragma unroll
        for (int nf = 0; nf < 4; ++nf) {
            bf16x8 bq = *(const bf16x8*)(Wallb + (size_t)((h * 4 + nf) * 8 + ks) * 512 + lane16);
            accq[0][nf] = __builtin_amdgcn_mfma_f32_16x16x32_bf16(aq[0], bq, accq[0][nf], 0, 0, 0);
            accq[1][nf] = __builtin_amdgcn_mfma_f32_16x16x32_bf16(aq[1], bq, accq[1][nf], 0, 0, 0);
            bf16x8 bkv = *(const bf16x8*)(Wallb + (size_t)((16 + sel * 4 + nf) * 8 + ks) * 512 + lane16);
            acckv[0][nf] = __builtin_amdgcn_mfma_f32_16x16x32_bf16(akv[0], bkv, acckv[0][nf], 0, 0, 0);
            acckv[1][nf] = __builtin_amdgcn_mfma_f32_16x16x32_bf16(akv[1], bkv, acckv[1][nf], 0, 0, 0);
        }
    }

    // ---- Q epilogue: rmsnorm + rope -> q_lds[h] --------------------------
    {
        float gw[4];
        #pragma unroll
        for (int nf = 0; nf < 4; ++nf) gw[nf] = wq[h * 64 + nf * 16 + li];
        #pragma unroll
        for (int mf = 0; mf < 2; ++mf) {
            #pragma unroll
            for (int r = 0; r < 4; ++r) {
                float x0 = accq[mf][0][r], x1 = accq[mf][1][r];
                float x2 = accq[mf][2][r], x3 = accq[mf][3][r];
                float ss = x0 * x0 + x1 * x1 + x2 * x2 + x3 * x3;
                ss += __shfl_xor(ss, 1);
                ss += __shfl_xor(ss, 2);
                ss += __shfl_xor(ss, 4);
                ss += __shfl_xor(ss, 8);
                const float rinv = rsqrtf(ss * (1.0f / 64.0f) + 1e-8f);
                const int tok = mf * 16 + g * 4 + r;
                const int t = t0 + tok;
                float v0 = x0 * rinv * gw[0];
                float v1 = x1 * rinv * gw[1];
                float v2 = x2 * rinv * gw[2];
                float v3 = x3 * rinv * gw[3];
                float2 cs = rtab[t * 8 + (li >> 1)];
                float px = __shfl_xor(v3, 1);
                v3 = ((li & 1) == 0) ? (v3 * cs.x - px * cs.y) : (px * cs.y + v3 * cs.x);
                char* qb = q_lds + h * 4096;
                const int sw = (tok & 7) << 4;
                *(unsigned short*)(qb + ((tok * 128 + (0 * 16 + li) * 2) ^ sw)) = f2bf(v0);
                *(unsigned short*)(qb + ((tok * 128 + (1 * 16 + li) * 2) ^ sw)) = f2bf(v1);
                *(unsigned short*)(qb + ((tok * 128 + (2 * 16 + li) * 2) ^ sw)) = f2bf(v2);
                *(unsigned short*)(qb + ((tok * 128 + (3 * 16 + li) * 2) ^ sw)) = f2bf(v3);
            }
        }
    }

    // ---- K/V epilogue: rmsnorm + rope -> k_lds / v_lds -------------------
    {
        float gw[4];
        #pragma unroll
        for (int nf = 0; nf < 4; ++nf)
            gw[nf] = (sel == 0) ? wk[nf * 16 + li] : wv[nf * 16 + li];
        #pragma unroll
        for (int mf = 0; mf < 2; ++mf) {
            #pragma unroll
            for (int r = 0; r < 4; ++r) {
                float x0 = acckv[mf][0][r], x1 = acckv[mf][1][r];
                float x2 = acckv[mf][2][r], x3 = acckv[mf][3][r];
                float ss = x0 * x0 + x1 * x1 + x2 * x2 + x3 * x3;
                ss += __shfl_xor(ss, 1);
                ss += __shfl_xor(ss, 2);
                ss += __shfl_xor(ss, 4);
                ss += __shfl_xor(ss, 8);
                const float rinv = rsqrtf(ss * (1.0f / 64.0f) + 1e-8f);
                const int row = base + mf * 16 + g * 4 + r;   // 0..63
                int tk = t0 - 16 + row;
                if (tk < 0) tk = 0;
                if (tk > T_SEQ - 1) tk = T_SEQ - 1;           // garbage rows only
                float v0 = x0 * rinv * gw[0];
                float v1 = x1 * rinv * gw[1];
                float v2 = x2 * rinv * gw[2];
                float v3 = x3 * rinv * gw[3];
                float2 cs = rtab[tk * 8 + (li >> 1)];
                float px = __shfl_xor(v3, 1);
                v3 = ((li & 1) == 0) ? (v3 * cs.x - px * cs.y) : (px * cs.y + v3 * cs.x);
                if (sel == 0) {
                    const int sw = (row & 7) << 4;
                    *(unsigned short*)(k_lds + ((row * 128 + (0 * 16 + li) * 2) ^ sw)) = f2bf(v0);
                    *(unsigned short*)(k_lds + ((row * 128 + (1 * 16 + li) * 2) ^ sw)) = f2bf(v1);
                    *(unsigned short*)(k_lds + ((row * 128 + (2 * 16 + li) * 2) ^ sw)) = f2bf(v2);
                    *(unsigned short*)(k_lds + ((row * 128 + (3 * 16 + li) * 2) ^ sw)) = f2bf(v3);
                } else {
                    const int sw = (row & 12) << 3;
                    *(unsigned short*)(v_lds + ((0 * 2048 + row * 32 + li * 2) ^ sw)) = f2bf(v0);
                    *(unsigned short*)(v_lds + ((1 * 2048 + row * 32 + li * 2) ^ sw)) = f2bf(v1);
                    *(unsigned short*)(v_lds + ((2 * 2048 + row * 32 + li * 2) ^ sw)) = f2bf(v2);
                    *(unsigned short*)(v_lds + ((3 * 2048 + row * 32 + li * 2) ^ sw)) = f2bf(v3);
                }
            }
        }
    }
    __syncthreads();

    // ---- attention: 2 passes of 16 tokens (th = 0,1), head h -------------
    #pragma unroll
    for (int th = 0; th < 2; ++th) {
        bf16x8 qf0, qf1;
        {
            const char* qb = q_lds + h * 4096;
            const int tok = th * 16 + li;
            const int sw = (tok & 7) << 4;
            qf0 = *(const bf16x8*)(qb + ((tok * 128 + g * 16) ^ sw));
            qf1 = *(const bf16x8*)(qb + ((tok * 128 + 64 + g * 16) ^ sw));
        }
        f32x4 st[2];
        #pragma unroll
        for (int tile = 0; tile < 2; ++tile) {
            const int row = th * 16 + tile * 16 + li;
            const int sw = (row & 7) << 4;
            bf16x8 kf0 = *(const bf16x8*)(k_lds + ((row * 128 + g * 16) ^ sw));
            bf16x8 kf1 = *(const bf16x8*)(k_lds + ((row * 128 + 64 + g * 16) ^ sw));
            f32x4 acc = {};
            acc = __builtin_amdgcn_mfma_f32_16x16x32_bf16(kf0, qf0, acc, 0, 0, 0);
            acc = __builtin_amdgcn_mfma_f32_16x16x32_bf16(kf1, qf1, acc, 0, 0, 0);
            st[tile] = acc;
        }

        float p[8];
        float mx = -1e30f;
        #pragma unroll
        for (int tile = 0; tile < 2; ++tile) {
            #pragma unroll
            for (int r = 0; r < 4; ++r) {
                int krel = tile * 16 - 16 + g * 4 + r;
                int dd = li - krel;
                bool ok = ((unsigned)dd < 16u) && (t0 + th * 16 + krel >= 0);
                float v = ok ? st[tile][r] * 0.125f : -1e30f;
                p[tile * 4 + r] = v;
                mx = fmaxf(mx, v);
            }
        }
        mx = fmaxf(mx, __shfl_xor(mx, 16));
        mx = fmaxf(mx, __shfl_xor(mx, 32));
        float sum = 0.f;
        #pragma unroll
        for (int i = 0; i < 8; ++i) { p[i] = __expf(p[i] - mx); sum += p[i]; }
        sum += __shfl_xor(sum, 16);
        sum += __shfl_xor(sum, 32);
        const float inv = 1.0f / sum;

        // P -> wave-local LDS relayout to K=32 A-fragment
        bf16x8 paf;
        {
            char* pbase = p_att + h * 1024;
            uint2 w0, w1;
            w0.x = (unsigned)f2bf(p[0] * inv) | ((unsigned)f2bf(p[1] * inv) << 16);
            w0.y = (unsigned)f2bf(p[2] * inv) | ((unsigned)f2bf(p[3] * inv) << 16);
            w1.x = (unsigned)f2bf(p[4] * inv) | ((unsigned)f2bf(p[5] * inv) << 16);
            w1.y = (unsigned)f2bf(p[6] * inv) | ((unsigned)f2bf(p[7] * inv) << 16);
            const int sw = (li & 3) << 4;
            asm volatile("s_waitcnt lgkmcnt(0)" ::: "memory");   // WAR vs prev pass
            *(uint2*)(pbase + ((li * 64 + 0 * 32 + g * 8) ^ sw)) = w0;
            *(uint2*)(pbase + ((li * 64 + 1 * 32 + g * 8) ^ sw)) = w1;
            asm volatile("s_waitcnt lgkmcnt(0)" ::: "memory");
            paf = *(const bf16x8*)(pbase + ((li * 64 + g * 16) ^ sw));
        }

        // PV: O[16 tok][64 ch]
        f32x4 o[4] = {};
        #pragma unroll
        for (int ctile = 0; ctile < 4; ++ctile) {
            bf16x8 vf;
            #pragma unroll
            for (int j = 0; j < 8; ++j) {
                int key = th * 16 + g * 8 + j;
                int byte = ctile * 2048 + key * 32 + li * 2;
                byte ^= (key & 12) << 3;
                vf[j] = *(const short*)(v_lds + byte);
            }
            o[ctile] = __builtin_amdgcn_mfma_f32_16x16x32_bf16(paf, vf, o[ctile], 0, 0, 0);
        }

        // inverse rope on chans 48..63; write O to swizzled LDS
        #pragma unroll
        for (int r = 0; r < 4; ++r) {
            const int row = th * 16 + g * 4 + r;
            const int t = t0 + row;
            float o3 = o[3][r];
            float po = __shfl_xor(o3, 1);
            float2 cs = rtab[t * 8 + (li >> 1)];
            o3 = ((li & 1) == 0) ? (o3 * cs.x + po * cs.y) : (-po * cs.y + o3 * cs.x);
            #pragma unroll
            for (int ctile = 0; ctile < 4; ++ctile) {
                const int col = h * 64 + ctile * 16 + li;
                int byte = row * 512 + col * 2;
                byte ^= (row & 7) << 4;
                float val = (ctile == 3) ? o3 : o[ctile][r];
                *(unsigned short*)(o_lds + byte) = f2bf(val);
            }
        }
    }
    __syncthreads();

    // ---- gates: wave h: gate=h>>1, half=h&1; 32 rows (acc[2][2]) ---------
    {
        const int gate = h >> 1, half = h & 1;
        const float* bg = gate ? bg1 : bg0;
        f32x4 accp[2][2] = {};
        #pragma unroll
        for (int ks = 0; ks < 4; ++ks) {
            const int k0 = ks * 32;
            bf16x8 a[2];
            #pragma unroll
            for (int mf = 0; mf < 2; ++mf) {
                const int row = mf * 16 + li;
                int byte = row * 512 + (gate * 128 + k0 + g * 8) * 2;
                byte ^= (row & 7) << 4;
                a[mf] = *(const bf16x8*)(o_lds + byte);
            }
            #pragma unroll
            for (int nf = 0; nf < 2; ++nf) {
                const int colblk = gate * 4 + half * 2 + nf;
                bf16x8 bfr = *(const bf16x8*)(Wpk2 + (size_t)(colblk * 4 + ks) * 512 + lane16);
                accp[0][nf] = __builtin_amdgcn_mfma_f32_16x16x32_bf16(a[0], bfr, accp[0][nf], 0, 0, 0);
                accp[1][nf] = __builtin_amdgcn_mfma_f32_16x16x32_bf16(a[1], bfr, accp[1][nf], 0, 0, 0);
            }
        }
        #pragma unroll
        for (int nf = 0; nf < 2; ++nf) {
            const int cl = half * 32 + nf * 16 + li;
            const int pcol = gate * 64 + cl;
            const float bb = bg[cl];
            #pragma unroll
            for (int mf = 0; mf < 2; ++mf) {
                #pragma unroll
                for (int r = 0; r < 4; ++r) {
                    const int row = mf * 16 + g * 4 + r;
                    int byte = row * 256 + pcol * 2;
                    byte ^= (row & 7) << 4;
                    *(unsigned short*)(p_lds + byte) = f2bf(accp[mf][nf][r] + bb);
                }
            }
        }
    }
    __syncthreads();

    // ---- out: wave h -> cols h*64..h*64+63, 32 rows (acc[2][4]) ----------
    {
        f32x4 acco[2][4] = {};
        #pragma unroll
        for (int ks = 0; ks < 4; ++ks) {
            const int k0 = ks * 32;
            bf16x8 a[2];
            #pragma unroll
            for (int mf = 0; mf < 2; ++mf) {
                const int row = mf * 16 + li;
                int byte = row * 256 + (k0 + g * 8) * 2;
                byte ^= (row & 7) << 4;
                a[mf] = *(const bf16x8*)(p_lds + byte);
            }
            #pragma unroll
            for (int nf = 0; nf < 4; ++nf) {
                const int colblk = 8 + h * 4 + nf;             // Wout at col 128
                bf16x8 bfr = *(const bf16x8*)(Wpk2 + (size_t)(colblk * 4 + ks) * 512 + lane16);
                acco[0][nf] = __builtin_amdgcn_mfma_f32_16x16x32_bf16(a[0], bfr, acco[0][nf], 0, 0, 0);
                acco[1][nf] = __builtin_amdgcn_mfma_f32_16x16x32_bf16(a[1], bfr, acco[1][nf], 0, 0, 0);
            }
        }
        #pragma unroll
        for (int nf = 0; nf < 4; ++nf) {
            const int col = h * 64 + nf * 16 + li;
            const float bb = bout[col];
            #pragma unroll
            for (int mf = 0; mf < 2; ++mf) {
                #pragma unroll
                for (int r = 0; r < 4; ++r) {
                    const int row = mf * 16 + g * 4 + r;
                    out[(size_t)(b * T_SEQ + t0 + row) * DMODEL + col] = acco[mf][nf][r] + bb;
                }
            }
        }
    }
}

extern "C" void kernel_launch(void* const* d_in, const int* in_sizes, int n_in,
                              void* d_out, int out_size, void* d_ws, size_t ws_size,
                              hipStream_t stream) {
    const float* H    = (const float*)d_in[0];
    const float* WQ   = (const float*)d_in[1];
    const float* WK   = (const float*)d_in[2];
    const float* WV   = (const float*)d_in[3];
    const float* wq   = (const float*)d_in[4];
    const float* wk   = (const float*)d_in[5];
    const float* wv   = (const float*)d_in[6];
    const float* Wg0  = (const float*)d_in[7];
    const float* bg0  = (const float*)d_in[8];
    const float* Wg1  = (const float*)d_in[9];
    const float* bg1  = (const float*)d_in[10];
    const float* Wout = (const float*)d_in[11];
    const float* bout = (const float*)d_in[12];
    float* out = (float*)d_out;

    char* ws = (char*)d_ws;
    unsigned short* Wallb = (unsigned short*)ws;          // 294,912 B
    float2* rtab = (float2*)(ws + 294912);                // 131,072 B

    conv_w_kernel<<<136, 256, 0, stream>>>(WQ, WK, WV, Wg0, Wg1, Wout, Wallb, rtab);
    fused_kernel<<<B_SZ * T_SEQ / 32, 256, 0, stream>>>(H, Wallb, wq, wk, wv, rtab,
                                                        bg0, bg1, bout, out);
}

// Round 10
// 22.773 us; speedup vs baseline: 1.6362x; 1.6362x over previous
//
#include <hip/hip_runtime.h>
#include <math.h>

#define T_SEQ 2048
#define DMODEL 256
#define C_HEAD 64
#define NH 4
#define NWIN 16
#define B_SZ 4

typedef __attribute__((ext_vector_type(8))) short bf16x8;
typedef __attribute__((ext_vector_type(8))) unsigned short ushort8;
typedef __attribute__((ext_vector_type(4))) float f32x4;

static __device__ __forceinline__ unsigned short f2bf(float f) {
    union { float f; unsigned int u; } v; v.f = f;
    unsigned int r = v.u + 0x7FFFu + ((v.u >> 16) & 1u);
    return (unsigned short)(r >> 16);
}

// ---------------- conv_w: pack weights fragment-major + rope table ------
// Region 1 (K=256): cols [WQ(256) WK(64) WV(64)]; Region 2 (K=128):
// cols [Wg0(64) Wg1(64) Wout(256)] at +98304. Fragment-major: every MFMA
// B-load is base + lane*16B. blocks 72..135: rope table (cos,sin).
__global__ __launch_bounds__(256) void conv_w_kernel(
    const float* __restrict__ WQ, const float* __restrict__ WK,
    const float* __restrict__ WV, const float* __restrict__ Wg0,
    const float* __restrict__ Wg1, const float* __restrict__ Wout,
    unsigned short* __restrict__ dst, float2* __restrict__ rtab) {
    const int tid = threadIdx.x;
    if (blockIdx.x >= 72) {
        const int idx = (blockIdx.x - 72) * 256 + tid;   // 0..16383
        const int t = idx >> 3, k = idx & 7;
        const float theta = powf(10000.0f, -0.125f * (float)k);
        const float fr = (float)t * theta;
        rtab[idx] = make_float2(cosf(fr), sinf(fr));
        return;
    }
    const int i = blockIdx.x * 256 + tid;               // 18432 vec8
    const float* s; long off; long doff;
    if (i < 12288) {                                    // K=256 region
        const long e = (long)i * 8;
        const int col = (int)(e >> 8), k = (int)(e & 255);
        if      (col < 256) { s = WQ; off = (long)col * 256 + k; }
        else if (col < 320) { s = WK; off = (long)(col - 256) * 256 + k; }
        else                { s = WV; off = (long)(col - 320) * 256 + k; }
        doff = ((long)(col >> 4) * 8 + (k >> 5)) * 512 + ((k >> 3) & 3) * 128 + (col & 15) * 8;
    } else {                                            // K=128 region
        const long e = (long)(i - 12288) * 8;
        const int col = (int)(e >> 7), k = (int)(e & 127);
        if      (col < 64)  { s = Wg0; off = (long)col * 128 + k; }
        else if (col < 128) { s = Wg1; off = (long)(col - 64) * 128 + k; }
        else                { s = Wout; off = (long)(col - 128) * 128 + k; }
        doff = 98304 + ((long)(col >> 4) * 4 + (k >> 5)) * 512 + ((k >> 3) & 3) * 128 + (col & 15) * 8;
    }
    const float4* s4 = (const float4*)(s + off);
    float4 a = s4[0], b = s4[1];
    ushort8 o;
    o[0] = f2bf(a.x); o[1] = f2bf(a.y); o[2] = f2bf(a.z); o[3] = f2bf(a.w);
    o[4] = f2bf(b.x); o[5] = f2bf(b.y); o[6] = f2bf(b.z); o[7] = f2bf(b.w);
    *(ushort8*)(dst + doff) = o;
}

// ---------------- fused kernel, BM=16, 8 waves -------------------------
// grid = B*(T/16) = 512 blocks, 512 thr (8 waves, 2 blocks/CU = 16 waves/CU).
// QKV: waves 0-3 = Q heads (acc[4], 32 MFMA); waves 4-7 = K/V row-halves.
// Attention (waves 0-3): S^T = mfma(K,Q), softmax, P relayout, PV, inv rope.
// Gates: 8 waves (gate x col-quarter). Out: 8 waves (32 cols each).
__global__ __launch_bounds__(512) void fused_kernel(
    const float* __restrict__ H, const unsigned short* __restrict__ Wallb,
    const float* __restrict__ wq, const float* __restrict__ wk,
    const float* __restrict__ wv, const float2* __restrict__ rtab,
    const float* __restrict__ bg0, const float* __restrict__ bg1,
    const float* __restrict__ bout, float* __restrict__ out)
{
    __shared__ __align__(16) char smem[36864];
    char* lds_a = smem;            // [32][512B] H staging (16KB)     [phase A]
    char* o_lds = smem;            // [16][512B] O tile (8KB)         [reuse]
    char* p_lds = smem + 8192;     // [16][256B] p tile (4KB)         [reuse]
    char* q_lds = smem + 16384;    // 4 heads x [16][128B] (8KB)
    char* k_lds = smem + 24576;    // [32][128B] (4KB)
    char* v_lds = smem + 28672;    // 4 ctiles x [32 keys][32B] (4KB)
    char* p_att = smem + 32768;    // 4 waves x 1KB

    const int tid = threadIdx.x;
    const int blk = blockIdx.x;
    const int b  = blk >> 7;
    const int t0 = (blk & 127) << 4;

    const unsigned short* Wpk2 = Wallb + 98304;   // K=128 packed region

    // ---- stage H rows [t0-16, t0+16) (clamped), f32 -> bf16, swizzled ----
    for (int idx = tid; idx < 1024; idx += 512) {
        int row = idx >> 5, ch = idx & 31;
        int t = t0 - 16 + row; if (t < 0) t = 0;       // masked later
        const float4* s4 = (const float4*)(H + ((size_t)b * T_SEQ + t) * DMODEL + ch * 8);
        float4 a = s4[0], c = s4[1];
        ushort8 o;
        o[0] = f2bf(a.x); o[1] = f2bf(a.y); o[2] = f2bf(a.z); o[3] = f2bf(a.w);
        o[4] = f2bf(c.x); o[5] = f2bf(c.y); o[6] = f2bf(c.z); o[7] = f2bf(c.w);
        int byte = row * 512 + ch * 16;
        byte ^= (row & 7) << 4;
        *(ushort8*)(lds_a + byte) = o;
    }
    __syncthreads();

    const int w  = tid >> 6;       // wave 0..7
    const int l  = tid & 63;
    const int g  = l >> 4;
    const int li = l & 15;
    const int lane16 = l * 8;      // packed-W per-lane elem offset (16B/lane)

    // ---- QKV: waves 0-3 Q heads; waves 4-7 K/V halves --------------------
    if (w < 4) {
        f32x4 acc[4] = {};
        #pragma unroll
        for (int ks = 0; ks < 8; ++ks) {
            const int row = 16 + li;               // tokens t0..t0+15
            int byte = row * 512 + (ks * 32 + g * 8) * 2;
            byte ^= (row & 7) << 4;
            bf16x8 a = *(const bf16x8*)(lds_a + byte);
            #pragma unroll
            for (int nf = 0; nf < 4; ++nf) {
                bf16x8 bq = *(const bf16x8*)(Wallb + (size_t)((w * 4 + nf) * 8 + ks) * 512 + lane16);
                acc[nf] = __builtin_amdgcn_mfma_f32_16x16x32_bf16(a, bq, acc[nf], 0, 0, 0);
            }
        }
        // Q epilogue: rmsnorm + rope -> q_lds[w]
        float gw[4];
        #pragma unroll
        for (int nf = 0; nf < 4; ++nf) gw[nf] = wq[w * 64 + nf * 16 + li];
        #pragma unroll
        for (int r = 0; r < 4; ++r) {
            float x0 = acc[0][r], x1 = acc[1][r];
            float x2 = acc[2][r], x3 = acc[3][r];
            float ss = x0 * x0 + x1 * x1 + x2 * x2 + x3 * x3;
            ss += __shfl_xor(ss, 1);
            ss += __shfl_xor(ss, 2);
            ss += __shfl_xor(ss, 4);
            ss += __shfl_xor(ss, 8);
            const float rinv = rsqrtf(ss * (1.0f / 64.0f) + 1e-8f);
            const int tok = g * 4 + r;
            const int t = t0 + tok;
            float v0 = x0 * rinv * gw[0];
            float v1 = x1 * rinv * gw[1];
            float v2 = x2 * rinv * gw[2];
            float v3 = x3 * rinv * gw[3];
            float2 cs = rtab[t * 8 + (li >> 1)];
            float px = __shfl_xor(v3, 1);
            v3 = ((li & 1) == 0) ? (v3 * cs.x - px * cs.y) : (px * cs.y + v3 * cs.x);
            char* qb = q_lds + w * 2048;
            const int sw = (tok & 7) << 4;
            *(unsigned short*)(qb + ((tok * 128 + (0 * 16 + li) * 2) ^ sw)) = f2bf(v0);
            *(unsigned short*)(qb + ((tok * 128 + (1 * 16 + li) * 2) ^ sw)) = f2bf(v1);
            *(unsigned short*)(qb + ((tok * 128 + (2 * 16 + li) * 2) ^ sw)) = f2bf(v2);
            *(unsigned short*)(qb + ((tok * 128 + (3 * 16 + li) * 2) ^ sw)) = f2bf(v3);
        }
    } else {
        const int sel = (w - 4) >> 1;      // 0 = K, 1 = V
        const int mfh = (w - 4) & 1;       // row half of 32-row halo
        f32x4 acc[4] = {};
        #pragma unroll
        for (int ks = 0; ks < 8; ++ks) {
            const int row = mfh * 16 + li;
            int byte = row * 512 + (ks * 32 + g * 8) * 2;
            byte ^= (row & 7) << 4;
            bf16x8 a = *(const bf16x8*)(lds_a + byte);
            #pragma unroll
            for (int nf = 0; nf < 4; ++nf) {
                bf16x8 bkv = *(const bf16x8*)(Wallb + (size_t)((16 + sel * 4 + nf) * 8 + ks) * 512 + lane16);
                acc[nf] = __builtin_amdgcn_mfma_f32_16x16x32_bf16(a, bkv, acc[nf], 0, 0, 0);
            }
        }
        // K/V epilogue: rmsnorm + rope -> k_lds / v_lds
        float gw[4];
        #pragma unroll
        for (int nf = 0; nf < 4; ++nf)
            gw[nf] = (sel == 0) ? wk[nf * 16 + li] : wv[nf * 16 + li];
        #pragma unroll
        for (int r = 0; r < 4; ++r) {
            float x0 = acc[0][r], x1 = acc[1][r];
            float x2 = acc[2][r], x3 = acc[3][r];
            float ss = x0 * x0 + x1 * x1 + x2 * x2 + x3 * x3;
            ss += __shfl_xor(ss, 1);
            ss += __shfl_xor(ss, 2);
            ss += __shfl_xor(ss, 4);
            ss += __shfl_xor(ss, 8);
            const float rinv = rsqrtf(ss * (1.0f / 64.0f) + 1e-8f);
            const int row = mfh * 16 + g * 4 + r;      // halo row 0..31
            int tk = t0 - 16 + row; if (tk < 0) tk = 0;
            float v0 = x0 * rinv * gw[0];
            float v1 = x1 * rinv * gw[1];
            float v2 = x2 * rinv * gw[2];
            float v3 = x3 * rinv * gw[3];
            float2 cs = rtab[tk * 8 + (li >> 1)];
            float px = __shfl_xor(v3, 1);
            v3 = ((li & 1) == 0) ? (v3 * cs.x - px * cs.y) : (px * cs.y + v3 * cs.x);
            if (sel == 0) {
                const int sw = (row & 7) << 4;
                *(unsigned short*)(k_lds + ((row * 128 + (0 * 16 + li) * 2) ^ sw)) = f2bf(v0);
                *(unsigned short*)(k_lds + ((row * 128 + (1 * 16 + li) * 2) ^ sw)) = f2bf(v1);
                *(unsigned short*)(k_lds + ((row * 128 + (2 * 16 + li) * 2) ^ sw)) = f2bf(v2);
                *(unsigned short*)(k_lds + ((row * 128 + (3 * 16 + li) * 2) ^ sw)) = f2bf(v3);
            } else {
                const int sw = (row & 12) << 3;
                *(unsigned short*)(v_lds + ((0 * 1024 + row * 32 + li * 2) ^ sw)) = f2bf(v0);
                *(unsigned short*)(v_lds + ((1 * 1024 + row * 32 + li * 2) ^ sw)) = f2bf(v1);
                *(unsigned short*)(v_lds + ((2 * 1024 + row * 32 + li * 2) ^ sw)) = f2bf(v2);
                *(unsigned short*)(v_lds + ((3 * 1024 + row * 32 + li * 2) ^ sw)) = f2bf(v3);
            }
        }
    }
    __syncthreads();

    // ---- attention (waves 0-3): head h = w -------------------------------
    if (w < 4) {
        const int h = w;
        bf16x8 qf0, qf1;
        {
            const char* qb = q_lds + h * 2048;
            const int sw = (li & 7) << 4;
            qf0 = *(const bf16x8*)(qb + ((li * 128 + g * 16) ^ sw));
            qf1 = *(const bf16x8*)(qb + ((li * 128 + 64 + g * 16) ^ sw));
        }
        f32x4 st[2];
        #pragma unroll
        for (int tile = 0; tile < 2; ++tile) {
            const int row = tile * 16 + li;
            const int sw = (row & 7) << 4;
            bf16x8 kf0 = *(const bf16x8*)(k_lds + ((row * 128 + g * 16) ^ sw));
            bf16x8 kf1 = *(const bf16x8*)(k_lds + ((row * 128 + 64 + g * 16) ^ sw));
            f32x4 acc = {};
            acc = __builtin_amdgcn_mfma_f32_16x16x32_bf16(kf0, qf0, acc, 0, 0, 0);
            acc = __builtin_amdgcn_mfma_f32_16x16x32_bf16(kf1, qf1, acc, 0, 0, 0);
            st[tile] = acc;
        }

        float p[8];
        float mx = -1e30f;
        #pragma unroll
        for (int tile = 0; tile < 2; ++tile) {
            #pragma unroll
            for (int r = 0; r < 4; ++r) {
                int krel = tile * 16 - 16 + g * 4 + r;
                int dd = li - krel;
                bool ok = ((unsigned)dd < 16u) && (t0 + krel >= 0);
                float v = ok ? st[tile][r] * 0.125f : -1e30f;
                p[tile * 4 + r] = v;
                mx = fmaxf(mx, v);
            }
        }
        mx = fmaxf(mx, __shfl_xor(mx, 16));
        mx = fmaxf(mx, __shfl_xor(mx, 32));
        float sum = 0.f;
        #pragma unroll
        for (int i = 0; i < 8; ++i) { p[i] = __expf(p[i] - mx); sum += p[i]; }
        sum += __shfl_xor(sum, 16);
        sum += __shfl_xor(sum, 32);
        const float inv = 1.0f / sum;

        // P -> wave-local LDS relayout to K=32 A-fragment
        bf16x8 paf;
        {
            char* pbase = p_att + h * 1024;
            uint2 w0, w1;
            w0.x = (unsigned)f2bf(p[0] * inv) | ((unsigned)f2bf(p[1] * inv) << 16);
            w0.y = (unsigned)f2bf(p[2] * inv) | ((unsigned)f2bf(p[3] * inv) << 16);
            w1.x = (unsigned)f2bf(p[4] * inv) | ((unsigned)f2bf(p[5] * inv) << 16);
            w1.y = (unsigned)f2bf(p[6] * inv) | ((unsigned)f2bf(p[7] * inv) << 16);
            const int sw = (li & 3) << 4;
            *(uint2*)(pbase + ((li * 64 + 0 * 32 + g * 8) ^ sw)) = w0;
            *(uint2*)(pbase + ((li * 64 + 1 * 32 + g * 8) ^ sw)) = w1;
            asm volatile("s_waitcnt lgkmcnt(0)" ::: "memory");
            paf = *(const bf16x8*)(pbase + ((li * 64 + g * 16) ^ sw));
        }

        // PV: O[16 tok][64 ch]
        f32x4 o[4] = {};
        #pragma unroll
        for (int ctile = 0; ctile < 4; ++ctile) {
            bf16x8 vf;
            #pragma unroll
            for (int j = 0; j < 8; ++j) {
                int key = g * 8 + j;
                int byte = ctile * 1024 + key * 32 + li * 2;
                byte ^= (key & 12) << 3;
                vf[j] = *(const short*)(v_lds + byte);
            }
            o[ctile] = __builtin_amdgcn_mfma_f32_16x16x32_bf16(paf, vf, o[ctile], 0, 0, 0);
        }

        // inverse rope on chans 48..63 (ctile 3); write O to swizzled LDS
        #pragma unroll
        for (int r = 0; r < 4; ++r) {
            const int row = g * 4 + r;
            const int t = t0 + row;
            float o3 = o[3][r];
            float po = __shfl_xor(o3, 1);
            float2 cs = rtab[t * 8 + (li >> 1)];
            o3 = ((li & 1) == 0) ? (o3 * cs.x + po * cs.y) : (-po * cs.y + o3 * cs.x);
            #pragma unroll
            for (int ctile = 0; ctile < 4; ++ctile) {
                const int col = h * 64 + ctile * 16 + li;
                int byte = row * 512 + col * 2;
                byte ^= (row & 7) << 4;
                float val = (ctile == 3) ? o3 : o[ctile][r];
                *(unsigned short*)(o_lds + byte) = f2bf(val);
            }
        }
    }
    __syncthreads();

    // ---- gates: 8 waves. wave w: gate=w>>2, col-quarter=w&3 --------------
    {
        const int gate = w >> 2, colq = w & 3;
        const float* bg = gate ? bg1 : bg0;
        f32x4 accp = {};
        #pragma unroll
        for (int ks = 0; ks < 4; ++ks) {
            int byte = li * 512 + (gate * 128 + ks * 32 + g * 8) * 2;
            byte ^= (li & 7) << 4;
            bf16x8 a = *(const bf16x8*)(o_lds + byte);
            const int colblk = gate * 4 + colq;
            bf16x8 bfr = *(const bf16x8*)(Wpk2 + (size_t)(colblk * 4 + ks) * 512 + lane16);
            accp = __builtin_amdgcn_mfma_f32_16x16x32_bf16(a, bfr, accp, 0, 0, 0);
        }
        const int cl = colq * 16 + li;
        const int pcol = gate * 64 + cl;
        const float bb = bg[cl];
        #pragma unroll
        for (int r = 0; r < 4; ++r) {
            const int row = g * 4 + r;
            int byte = row * 256 + pcol * 2;
            byte ^= (row & 7) << 4;
            *(unsigned short*)(p_lds + byte) = f2bf(accp[r] + bb);
        }
    }
    __syncthreads();

    // ---- out: 8 waves. wave w -> cols w*32 .. w*32+31 --------------------
    {
        f32x4 acco[2] = {};
        #pragma unroll
        for (int ks = 0; ks < 4; ++ks) {
            int byte = li * 256 + (ks * 32 + g * 8) * 2;
            byte ^= (li & 7) << 4;
            bf16x8 a = *(const bf16x8*)(p_lds + byte);
            #pragma unroll
            for (int nf = 0; nf < 2; ++nf) {
                const int colblk = 8 + w * 2 + nf;             // Wout at col 128
                bf16x8 bfr = *(const bf16x8*)(Wpk2 + (size_t)(colblk * 4 + ks) * 512 + lane16);
                acco[nf] = __builtin_amdgcn_mfma_f32_16x16x32_bf16(a, bfr, acco[nf], 0, 0, 0);
            }
        }
        #pragma unroll
        for (int nf = 0; nf < 2; ++nf) {
            const int col = w * 32 + nf * 16 + li;
            const float bb = bout[col];
            #pragma unroll
            for (int r = 0; r < 4; ++r) {
                const int row = g * 4 + r;
                out[(size_t)(b * T_SEQ + t0 + row) * DMODEL + col] = acco[nf][r] + bb;
            }
        }
    }
}

extern "C" void kernel_launch(void* const* d_in, const int* in_sizes, int n_in,
                              void* d_out, int out_size, void* d_ws, size_t ws_size,
                              hipStream_t stream) {
    const float* H    = (const float*)d_in[0];
    const float* WQ   = (const float*)d_in[1];
    const float* WK   = (const float*)d_in[2];
    const float* WV   = (const float*)d_in[3];
    const float* wq   = (const float*)d_in[4];
    const float* wk   = (const float*)d_in[5];
    const float* wv   = (const float*)d_in[6];
    const float* Wg0  = (const float*)d_in[7];
    const float* bg0  = (const float*)d_in[8];
    const float* Wg1  = (const float*)d_in[9];
    const float* bg1  = (const float*)d_in[10];
    const float* Wout = (const float*)d_in[11];
    const float* bout = (const float*)d_in[12];
    float* out = (float*)d_out;

    char* ws = (char*)d_ws;
    unsigned short* Wallb = (unsigned short*)ws;          // 294,912 B
    float2* rtab = (float2*)(ws + 294912);                // 131,072 B

    conv_w_kernel<<<136, 256, 0, stream>>>(WQ, WK, WV, Wg0, Wg1, Wout, Wallb, rtab);
    fused_kernel<<<B_SZ * T_SEQ / 16, 512, 0, stream>>>(H, Wallb, wq, wk, wv, rtab,
                                                        bg0, bg1, bout, out);
}

// Round 11
// 22.107 us; speedup vs baseline: 1.6855x; 1.0301x over previous
//
#include <hip/hip_runtime.h>
#include <math.h>

#define T_SEQ 2048
#define DMODEL 256
#define C_HEAD 64
#define NH 4
#define NWIN 16
#define B_SZ 4

typedef __attribute__((ext_vector_type(8))) short bf16x8;
typedef __attribute__((ext_vector_type(8))) unsigned short ushort8;
typedef __attribute__((ext_vector_type(4))) float f32x4;

static __device__ __forceinline__ unsigned short f2bf(float f) {
    union { float f; unsigned int u; } v; v.f = f;
    unsigned int r = v.u + 0x7FFFu + ((v.u >> 16) & 1u);
    return (unsigned short)(r >> 16);
}

// ---------------- conv_w: pack weights fragment-major + rope table ------
__global__ __launch_bounds__(256) void conv_w_kernel(
    const float* __restrict__ WQ, const float* __restrict__ WK,
    const float* __restrict__ WV, const float* __restrict__ Wg0,
    const float* __restrict__ Wg1, const float* __restrict__ Wout,
    unsigned short* __restrict__ dst, float2* __restrict__ rtab) {
    const int tid = threadIdx.x;
    if (blockIdx.x >= 72) {
        const int idx = (blockIdx.x - 72) * 256 + tid;   // 0..16383
        const int t = idx >> 3, k = idx & 7;
        const float theta = powf(10000.0f, -0.125f * (float)k);
        const float fr = (float)t * theta;
        rtab[idx] = make_float2(cosf(fr), sinf(fr));
        return;
    }
    const int i = blockIdx.x * 256 + tid;               // 18432 vec8
    const float* s; long off; long doff;
    if (i < 12288) {                                    // K=256 region
        const long e = (long)i * 8;
        const int col = (int)(e >> 8), k = (int)(e & 255);
        if      (col < 256) { s = WQ; off = (long)col * 256 + k; }
        else if (col < 320) { s = WK; off = (long)(col - 256) * 256 + k; }
        else                { s = WV; off = (long)(col - 320) * 256 + k; }
        doff = ((long)(col >> 4) * 8 + (k >> 5)) * 512 + ((k >> 3) & 3) * 128 + (col & 15) * 8;
    } else {                                            // K=128 region
        const long e = (long)(i - 12288) * 8;
        const int col = (int)(e >> 7), k = (int)(e & 127);
        if      (col < 64)  { s = Wg0; off = (long)col * 128 + k; }
        else if (col < 128) { s = Wg1; off = (long)(col - 64) * 128 + k; }
        else                { s = Wout; off = (long)(col - 128) * 128 + k; }
        doff = 98304 + ((long)(col >> 4) * 4 + (k >> 5)) * 512 + ((k >> 3) & 3) * 128 + (col & 15) * 8;
    }
    const float4* s4 = (const float4*)(s + off);
    float4 a = s4[0], b = s4[1];
    ushort8 o;
    o[0] = f2bf(a.x); o[1] = f2bf(a.y); o[2] = f2bf(a.z); o[3] = f2bf(a.w);
    o[4] = f2bf(b.x); o[5] = f2bf(b.y); o[6] = f2bf(b.z); o[7] = f2bf(b.w);
    *(ushort8*)(dst + doff) = o;
}

// ---------------- fused kernel, BM=32, 16 waves -------------------------
// grid = B*(T/32) = 256 blocks, 1024 thr. Same 4096 total waves / 16
// waves-per-CU as R10, but weight L2 traffic halved.
// QKV: waves 0-7 = Q (head=w>>1, tok-half=w&1); waves 8-13 = K/V 16-row
// slabs of the 48-row halo; waves 14-15 idle.
// Attention: waves 0-7 (head, tok-half). V is stored TRANSPOSED
// (V^T[64 ch][48 keys], 112B stride) so PV B-frags are single b128 reads.
// Gates: 16 waves (gate x colq x rowhalf). Out: 16 waves (16 cols each).
__global__ __launch_bounds__(1024) void fused_kernel(
    const float* __restrict__ H, const unsigned short* __restrict__ Wallb,
    const float* __restrict__ wq, const float* __restrict__ wk,
    const float* __restrict__ wv, const float2* __restrict__ rtab,
    const float* __restrict__ bg0, const float* __restrict__ bg1,
    const float* __restrict__ bout, float* __restrict__ out)
{
    __shared__ __align__(16) char smem[62464];
    char* lds_a = smem;            // [48][512B] H staging (24KB)   [phase A]
    char* o_lds = smem;            // [32][512B] O tile (16KB)      [reuse]
    char* p_lds = smem + 16384;    // [32][256B] p tile (8KB)       [reuse]
    char* q_lds = smem + 24576;    // 4 heads x [32][128B] (16KB)
    char* k_lds = smem + 40960;    // [48][128B] (6KB)
    char* v_t   = smem + 47104;    // V^T [64 ch][112B stride] (7KB)
    char* p_att = smem + 54272;    // 8 Q-waves x 1KB

    const int tid = threadIdx.x;
    const int blk = blockIdx.x;
    const int b  = blk >> 6;
    const int t0 = (blk & 63) << 5;

    const unsigned short* Wpk2 = Wallb + 98304;   // K=128 packed region

    // ---- stage H rows [t0-16, t0+32) (48 rows, clamped), f32->bf16 ------
    for (int idx = tid; idx < 1536; idx += 1024) {
        int row = idx >> 5, ch = idx & 31;
        int t = t0 - 16 + row; if (t < 0) t = 0;       // masked later
        const float4* s4 = (const float4*)(H + ((size_t)b * T_SEQ + t) * DMODEL + ch * 8);
        float4 a = s4[0], c = s4[1];
        ushort8 o;
        o[0] = f2bf(a.x); o[1] = f2bf(a.y); o[2] = f2bf(a.z); o[3] = f2bf(a.w);
        o[4] = f2bf(c.x); o[5] = f2bf(c.y); o[6] = f2bf(c.z); o[7] = f2bf(c.w);
        int byte = row * 512 + ch * 16;
        byte ^= (row & 7) << 4;
        *(ushort8*)(lds_a + byte) = o;
    }
    __syncthreads();

    const int w  = tid >> 6;       // wave 0..15
    const int l  = tid & 63;
    const int g  = l >> 4;
    const int li = l & 15;
    const int lane16 = l * 8;      // packed-W per-lane elem offset (16B/lane)

    // ---- QKV ------------------------------------------------------------
    if (w < 8) {
        const int h  = w >> 1;
        const int th = w & 1;                      // token half
        f32x4 acc[4] = {};
        #pragma unroll
        for (int ks = 0; ks < 8; ++ks) {
            const int row = 16 + th * 16 + li;     // token rows
            int byte = row * 512 + (ks * 32 + g * 8) * 2;
            byte ^= (row & 7) << 4;
            bf16x8 a = *(const bf16x8*)(lds_a + byte);
            #pragma unroll
            for (int nf = 0; nf < 4; ++nf) {
                bf16x8 bq = *(const bf16x8*)(Wallb + (size_t)((h * 4 + nf) * 8 + ks) * 512 + lane16);
                acc[nf] = __builtin_amdgcn_mfma_f32_16x16x32_bf16(a, bq, acc[nf], 0, 0, 0);
            }
        }
        float gw[4];
        #pragma unroll
        for (int nf = 0; nf < 4; ++nf) gw[nf] = wq[h * 64 + nf * 16 + li];
        #pragma unroll
        for (int r = 0; r < 4; ++r) {
            float x0 = acc[0][r], x1 = acc[1][r];
            float x2 = acc[2][r], x3 = acc[3][r];
            float ss = x0 * x0 + x1 * x1 + x2 * x2 + x3 * x3;
            ss += __shfl_xor(ss, 1);
            ss += __shfl_xor(ss, 2);
            ss += __shfl_xor(ss, 4);
            ss += __shfl_xor(ss, 8);
            const float rinv = rsqrtf(ss * (1.0f / 64.0f) + 1e-8f);
            const int tok = th * 16 + g * 4 + r;   // 0..31
            const int t = t0 + tok;
            float v0 = x0 * rinv * gw[0];
            float v1 = x1 * rinv * gw[1];
            float v2 = x2 * rinv * gw[2];
            float v3 = x3 * rinv * gw[3];
            float2 cs = rtab[t * 8 + (li >> 1)];
            float px = __shfl_xor(v3, 1);
            v3 = ((li & 1) == 0) ? (v3 * cs.x - px * cs.y) : (px * cs.y + v3 * cs.x);
            char* qb = q_lds + h * 4096;
            const int sw = (tok & 7) << 4;
            *(unsigned short*)(qb + ((tok * 128 + (0 * 16 + li) * 2) ^ sw)) = f2bf(v0);
            *(unsigned short*)(qb + ((tok * 128 + (1 * 16 + li) * 2) ^ sw)) = f2bf(v1);
            *(unsigned short*)(qb + ((tok * 128 + (2 * 16 + li) * 2) ^ sw)) = f2bf(v2);
            *(unsigned short*)(qb + ((tok * 128 + (3 * 16 + li) * 2) ^ sw)) = f2bf(v3);
        }
    } else if (w < 14) {
        const int idx  = w - 8;
        const int sel  = (idx >= 3) ? 1 : 0;       // 0 = K, 1 = V
        const int slab = sel ? (idx - 3) : idx;    // 16-row slab 0..2
        f32x4 acc[4] = {};
        #pragma unroll
        for (int ks = 0; ks < 8; ++ks) {
            const int row = slab * 16 + li;        // halo rows 0..47
            int byte = row * 512 + (ks * 32 + g * 8) * 2;
            byte ^= (row & 7) << 4;
            bf16x8 a = *(const bf16x8*)(lds_a + byte);
            #pragma unroll
            for (int nf = 0; nf < 4; ++nf) {
                bf16x8 bkv = *(const bf16x8*)(Wallb + (size_t)((16 + sel * 4 + nf) * 8 + ks) * 512 + lane16);
                acc[nf] = __builtin_amdgcn_mfma_f32_16x16x32_bf16(a, bkv, acc[nf], 0, 0, 0);
            }
        }
        float gw[4];
        #pragma unroll
        for (int nf = 0; nf < 4; ++nf)
            gw[nf] = (sel == 0) ? wk[nf * 16 + li] : wv[nf * 16 + li];
        #pragma unroll
        for (int r = 0; r < 4; ++r) {
            float x0 = acc[0][r], x1 = acc[1][r];
            float x2 = acc[2][r], x3 = acc[3][r];
            float ss = x0 * x0 + x1 * x1 + x2 * x2 + x3 * x3;
            ss += __shfl_xor(ss, 1);
            ss += __shfl_xor(ss, 2);
            ss += __shfl_xor(ss, 4);
            ss += __shfl_xor(ss, 8);
            const float rinv = rsqrtf(ss * (1.0f / 64.0f) + 1e-8f);
            const int row = slab * 16 + g * 4 + r;     // halo row 0..47
            int tk = t0 - 16 + row; if (tk < 0) tk = 0;
            float v0 = x0 * rinv * gw[0];
            float v1 = x1 * rinv * gw[1];
            float v2 = x2 * rinv * gw[2];
            float v3 = x3 * rinv * gw[3];
            float2 cs = rtab[tk * 8 + (li >> 1)];
            float px = __shfl_xor(v3, 1);
            v3 = ((li & 1) == 0) ? (v3 * cs.x - px * cs.y) : (px * cs.y + v3 * cs.x);
            if (sel == 0) {
                const int sw = (row & 7) << 4;
                *(unsigned short*)(k_lds + ((row * 128 + (0 * 16 + li) * 2) ^ sw)) = f2bf(v0);
                *(unsigned short*)(k_lds + ((row * 128 + (1 * 16 + li) * 2) ^ sw)) = f2bf(v1);
                *(unsigned short*)(k_lds + ((row * 128 + (2 * 16 + li) * 2) ^ sw)) = f2bf(v2);
                *(unsigned short*)(k_lds + ((row * 128 + (3 * 16 + li) * 2) ^ sw)) = f2bf(v3);
            } else {
                // V^T[ch][key], 112B row stride (2-way-conflict free)
                *(unsigned short*)(v_t + (0 * 16 + li) * 112 + row * 2) = f2bf(v0);
                *(unsigned short*)(v_t + (1 * 16 + li) * 112 + row * 2) = f2bf(v1);
                *(unsigned short*)(v_t + (2 * 16 + li) * 112 + row * 2) = f2bf(v2);
                *(unsigned short*)(v_t + (3 * 16 + li) * 112 + row * 2) = f2bf(v3);
            }
        }
    }
    __syncthreads();

    // ---- attention: waves 0-7, head h = w>>1, token half th = w&1 --------
    if (w < 8) {
        const int h  = w >> 1;
        const int th = w & 1;
        bf16x8 qf0, qf1;
        {
            const char* qb = q_lds + h * 4096;
            const int tok = th * 16 + li;
            const int sw = (tok & 7) << 4;
            qf0 = *(const bf16x8*)(qb + ((tok * 128 + g * 16) ^ sw));
            qf1 = *(const bf16x8*)(qb + ((tok * 128 + 64 + g * 16) ^ sw));
        }
        f32x4 st[2];
        #pragma unroll
        for (int tile = 0; tile < 2; ++tile) {
            const int row = th * 16 + tile * 16 + li;  // halo key row
            const int sw = (row & 7) << 4;
            bf16x8 kf0 = *(const bf16x8*)(k_lds + ((row * 128 + g * 16) ^ sw));
            bf16x8 kf1 = *(const bf16x8*)(k_lds + ((row * 128 + 64 + g * 16) ^ sw));
            f32x4 acc = {};
            acc = __builtin_amdgcn_mfma_f32_16x16x32_bf16(kf0, qf0, acc, 0, 0, 0);
            acc = __builtin_amdgcn_mfma_f32_16x16x32_bf16(kf1, qf1, acc, 0, 0, 0);
            st[tile] = acc;
        }

        float p[8];
        float mx = -1e30f;
        #pragma unroll
        for (int tile = 0; tile < 2; ++tile) {
            #pragma unroll
            for (int r = 0; r < 4; ++r) {
                int krel = tile * 16 - 16 + g * 4 + r;    // key - token_base
                int dd = li - krel;                        // token - key
                bool ok = ((unsigned)dd < 16u) && (t0 + th * 16 + krel >= 0);
                float v = ok ? st[tile][r] * 0.125f : -1e30f;
                p[tile * 4 + r] = v;
                mx = fmaxf(mx, v);
            }
        }
        mx = fmaxf(mx, __shfl_xor(mx, 16));
        mx = fmaxf(mx, __shfl_xor(mx, 32));
        float sum = 0.f;
        #pragma unroll
        for (int i = 0; i < 8; ++i) { p[i] = __expf(p[i] - mx); sum += p[i]; }
        sum += __shfl_xor(sum, 16);
        sum += __shfl_xor(sum, 32);
        const float inv = 1.0f / sum;

        // P -> wave-local LDS relayout to K=32 A-fragment
        bf16x8 paf;
        {
            char* pbase = p_att + w * 1024;
            uint2 w0, w1;
            w0.x = (unsigned)f2bf(p[0] * inv) | ((unsigned)f2bf(p[1] * inv) << 16);
            w0.y = (unsigned)f2bf(p[2] * inv) | ((unsigned)f2bf(p[3] * inv) << 16);
            w1.x = (unsigned)f2bf(p[4] * inv) | ((unsigned)f2bf(p[5] * inv) << 16);
            w1.y = (unsigned)f2bf(p[6] * inv) | ((unsigned)f2bf(p[7] * inv) << 16);
            const int sw = (li & 3) << 4;
            *(uint2*)(pbase + ((li * 64 + 0 * 32 + g * 8) ^ sw)) = w0;
            *(uint2*)(pbase + ((li * 64 + 1 * 32 + g * 8) ^ sw)) = w1;
            asm volatile("s_waitcnt lgkmcnt(0)" ::: "memory");
            paf = *(const bf16x8*)(pbase + ((li * 64 + g * 16) ^ sw));
        }

        // PV: B-fragment = V^T row segment, single b128 per ctile
        f32x4 o[4] = {};
        #pragma unroll
        for (int ctile = 0; ctile < 4; ++ctile) {
            bf16x8 vf = *(const bf16x8*)(v_t + (ctile * 16 + li) * 112 + th * 32 + g * 16);
            o[ctile] = __builtin_amdgcn_mfma_f32_16x16x32_bf16(paf, vf, o[ctile], 0, 0, 0);
        }

        // inverse rope on chans 48..63 (ctile 3); write O to swizzled LDS
        #pragma unroll
        for (int r = 0; r < 4; ++r) {
            const int row = th * 16 + g * 4 + r;       // 0..31
            const int t = t0 + row;
            float o3 = o[3][r];
            float po = __shfl_xor(o3, 1);
            float2 cs = rtab[t * 8 + (li >> 1)];
            o3 = ((li & 1) == 0) ? (o3 * cs.x + po * cs.y) : (-po * cs.y + o3 * cs.x);
            #pragma unroll
            for (int ctile = 0; ctile < 4; ++ctile) {
                const int col = h * 64 + ctile * 16 + li;
                int byte = row * 512 + col * 2;
                byte ^= (row & 7) << 4;
                float val = (ctile == 3) ? o3 : o[ctile][r];
                *(unsigned short*)(o_lds + byte) = f2bf(val);
            }
        }
    }
    __syncthreads();

    // ---- gates: 16 waves. gate=(w>>3), colq=(w>>1)&3, rowhalf=w&1 --------
    {
        const int gate = (w >> 3) & 1, colq = (w >> 1) & 3, rh = w & 1;
        const float* bg = gate ? bg1 : bg0;
        f32x4 accp = {};
        #pragma unroll
        for (int ks = 0; ks < 4; ++ks) {
            const int row = rh * 16 + li;
            int byte = row * 512 + (gate * 128 + ks * 32 + g * 8) * 2;
            byte ^= (row & 7) << 4;
            bf16x8 a = *(const bf16x8*)(o_lds + byte);
            const int colblk = gate * 4 + colq;
            bf16x8 bfr = *(const bf16x8*)(Wpk2 + (size_t)(colblk * 4 + ks) * 512 + lane16);
            accp = __builtin_amdgcn_mfma_f32_16x16x32_bf16(a, bfr, accp, 0, 0, 0);
        }
        const int cl = colq * 16 + li;
        const int pcol = gate * 64 + cl;
        const float bb = bg[cl];
        #pragma unroll
        for (int r = 0; r < 4; ++r) {
            const int row = rh * 16 + g * 4 + r;
            int byte = row * 256 + pcol * 2;
            byte ^= (row & 7) << 4;
            *(unsigned short*)(p_lds + byte) = f2bf(accp[r] + bb);
        }
    }
    __syncthreads();

    // ---- out: 16 waves. wave w -> cols w*16 .. w*16+15, 32 rows ----------
    {
        f32x4 acco[2] = {};
        #pragma unroll
        for (int ks = 0; ks < 4; ++ks) {
            bf16x8 a[2];
            #pragma unroll
            for (int mf = 0; mf < 2; ++mf) {
                const int row = mf * 16 + li;
                int byte = row * 256 + (ks * 32 + g * 8) * 2;
                byte ^= (row & 7) << 4;
                a[mf] = *(const bf16x8*)(p_lds + byte);
            }
            const int colblk = 8 + w;                  // Wout at col 128
            bf16x8 bfr = *(const bf16x8*)(Wpk2 + (size_t)(colblk * 4 + ks) * 512 + lane16);
            acco[0] = __builtin_amdgcn_mfma_f32_16x16x32_bf16(a[0], bfr, acco[0], 0, 0, 0);
            acco[1] = __builtin_amdgcn_mfma_f32_16x16x32_bf16(a[1], bfr, acco[1], 0, 0, 0);
        }
        const int col = w * 16 + li;
        const float bb = bout[col];
        #pragma unroll
        for (int mf = 0; mf < 2; ++mf) {
            #pragma unroll
            for (int r = 0; r < 4; ++r) {
                const int row = mf * 16 + g * 4 + r;
                out[(size_t)(b * T_SEQ + t0 + row) * DMODEL + col] = acco[mf][r] + bb;
            }
        }
    }
}

extern "C" void kernel_launch(void* const* d_in, const int* in_sizes, int n_in,
                              void* d_out, int out_size, void* d_ws, size_t ws_size,
                              hipStream_t stream) {
    const float* H    = (const float*)d_in[0];
    const float* WQ   = (const float*)d_in[1];
    const float* WK   = (const float*)d_in[2];
    const float* WV   = (const float*)d_in[3];
    const float* wq   = (const float*)d_in[4];
    const float* wk   = (const float*)d_in[5];
    const float* wv   = (const float*)d_in[6];
    const float* Wg0  = (const float*)d_in[7];
    const float* bg0  = (const float*)d_in[8];
    const float* Wg1  = (const float*)d_in[9];
    const float* bg1  = (const float*)d_in[10];
    const float* Wout = (const float*)d_in[11];
    const float* bout = (const float*)d_in[12];
    float* out = (float*)d_out;

    char* ws = (char*)d_ws;
    unsigned short* Wallb = (unsigned short*)ws;          // 294,912 B
    float2* rtab = (float2*)(ws + 294912);                // 131,072 B

    conv_w_kernel<<<136, 256, 0, stream>>>(WQ, WK, WV, Wg0, Wg1, Wout, Wallb, rtab);
    fused_kernel<<<B_SZ * T_SEQ / 32, 1024, 0, stream>>>(H, Wallb, wq, wk, wv, rtab,
                                                         bg0, bg1, bout, out);
}